// Round 23
// baseline (48.271 us; speedup 1.0000x reference)
//
#include <hip/hip_runtime.h>
#include <hip/hip_bf16.h>
#include <stdint.h>

typedef __attribute__((ext_vector_type(8))) short bf16x8;
typedef __attribute__((ext_vector_type(16))) float f32x16;
using bf16 = __hip_bfloat16;

static constexpr int Mdim = 512;   // A batch
static constexpr int Ndim = 64;    // B batch
static constexpr int Cdim = 128;   // channels (K of the GEMM)
static constexpr int Pdim = 64;    // H*W positions
static constexpr float EPS_ADD = 0.001f;

// ---------------------------------------------------------------------------
// async global->LDS, 16B per lane
// ---------------------------------------------------------------------------
__device__ __forceinline__ void gll16(const void* gsrc, void* ldst) {
    const __attribute__((address_space(1))) unsigned int* g =
        (const __attribute__((address_space(1))) unsigned int*)gsrc;
    __attribute__((address_space(3))) unsigned int* l =
        (__attribute__((address_space(3))) unsigned int*)(uintptr_t)ldst;
    __builtin_amdgcn_global_load_lds(g, l, 16, 0, 0);
}

// ---------------------------------------------------------------------------
// prep (fused, UNCHANGED — verified): fragment-ordered outputs.
//   A-tile (per m): idx = h*4096 + ks*512 + lane*8 + e
//   G-tile (per n): idx = qt*4096 + ks*512 + lane*8 + e
// ---------------------------------------------------------------------------
__global__ void prep_kernel(const float* __restrict__ A, const float* __restrict__ B,
                            const float* __restrict__ Wg,
                            bf16* __restrict__ Afrag, bf16* __restrict__ Gfrag) {
    __shared__ float lds[128 * 65];
    const int t = threadIdx.x;

    if (blockIdx.x < 512) {
        const int m = blockIdx.x;
        const float* __restrict__ Am = A + (size_t)m * (Cdim * Pdim);
#pragma unroll
        for (int i = 0; i < 8; ++i) {
            int v = t + i * 256;
            int gidx = v * 4;
            int c = gidx >> 6, p = gidx & 63;
            float4 val = *reinterpret_cast<const float4*>(Am + gidx);
            float* dst = &lds[c * 65 + p];
            dst[0] = val.x; dst[1] = val.y; dst[2] = val.z; dst[3] = val.w;
        }
        __syncthreads();

        unsigned* __restrict__ dst32 = (unsigned*)(Afrag + (size_t)m * 8192);
#pragma unroll
        for (int i = 0; i < 16; ++i) {
            int pr = t + i * 256;
            int p = pr >> 6;
            int c = (pr & 63) << 1;
            float f0 = lds[c * 65 + p];
            float f1 = lds[(c + 1) * 65 + p];
            union { bf16 hh[2]; unsigned u; } pk;
            pk.hh[0] = __float2bfloat16(f0);
            pk.hh[1] = __float2bfloat16(f1);
            int h = p >> 5, l31 = p & 31;
            int ks = c >> 4, hi = (c >> 3) & 1, e = c & 7;
            dst32[h * 2048 + ks * 256 + hi * 128 + l31 * 4 + (e >> 1)] = pk.u;
        }
    } else {
        const int nb = blockIdx.x - 512;
        const int n  = nb >> 2;
        const int q0 = (nb & 3) * 16;
        const float* __restrict__ Bn = B + (size_t)n * (Cdim * Pdim);
#pragma unroll
        for (int i = 0; i < 8; ++i) {
            int v = t + i * 256;
            int gidx = v * 4;
            int c = gidx >> 6, q = gidx & 63;
            float4 val = *reinterpret_cast<const float4*>(Bn + gidx);
            float* dst = &lds[c * 65 + q];
            dst[0] = val.x; dst[1] = val.y; dst[2] = val.z; dst[3] = val.w;
        }
        __syncthreads();

        const int d  = t & 127;
        const int qb = q0 + (t >> 7) * 8;
        float acc[8] = {0.f, 0.f, 0.f, 0.f, 0.f, 0.f, 0.f, 0.f};
        for (int c = 0; c < 128; ++c) {
            float w = Wg[c * 128 + d];
#pragma unroll
            for (int qi = 0; qi < 8; ++qi)
                acc[qi] = fmaf(lds[c * 65 + qb + qi], w, acc[qi]);
        }
        bf16* __restrict__ gdst = Gfrag + (size_t)n * 8192;
        const int ks = d >> 4, hi = (d >> 3) & 1, e = d & 7;
#pragma unroll
        for (int qi = 0; qi < 8; ++qi) {
            int q = qb + qi;
            int qt = q >> 5, l31 = q & 31;
            gdst[qt * 4096 + ks * 512 + hi * 256 + l31 * 8 + e] = __float2bfloat16(acc[qi]);
        }
    }
}

// ---------------------------------------------------------------------------
// gemm_max v20: v19 body, 2x prologue amortization.
//  - Block = 512 thr (8 waves) = BM=8 m's x BN=4 n's. The 64KB G-stage +
//    vmcnt(0) drain + barrier (v19's hidden half-cost) now serves 8 m's:
//    prologue per unit compute halves; block count halves (1024); G-stage
//    traffic halves.
//  - Steady state unchanged from v19: 4 free-running bodies of pure
//    {16 ds_read (static offsets) -> 32 MFMA -> reduce -> store};
//    zero barriers / waitcnt / setprio after the single prologue barrier;
//    sG read-only afterward.
//  - LDS 64KB -> 2 blocks/CU resident (4 slots queued): one block's
//    prologue drain overlaps the other's compute.
//  - Grid 1024 = 16 bn x 64 mg; bid%8 = mg%8 (same-A blocks on one XCD).
// MFMA 32x32x16, mfma(G,A): D col = lane&31 = p, row = q (m74/m101).
// ---------------------------------------------------------------------------
__global__ __launch_bounds__(512, 2)
void gemm_max_kernel(const bf16* __restrict__ Afrag, const bf16* __restrict__ Gfrag,
                     float* __restrict__ out) {
    __shared__ bf16 sG[4][8192];          // 64KB static, fragment order
    const int tid  = threadIdx.x;
    const int lane = tid & 63;
    const int wv   = tid >> 6;            // 0..7
    const int mi = wv >> 1, h = wv & 1;   // wave: m-pair index (0..3), p-half
    const int l31 = lane & 31, hi = lane >> 5;
    const int mg = blockIdx.x & 63;       // 64 m-groups of 8
    const int bn = blockIdx.x >> 6;       // 16 n-groups of 4
    const int m0 = mg * 8 + mi * 2;       // wave handles m0, m0+1

    // ---- prologue: A-loads + full G-stage, one drain, one barrier ----
    bf16x8 a[2][8];                       // [m-sub][ks]
#pragma unroll
    for (int u = 0; u < 2; ++u) {
        const bf16* Ap = Afrag + (size_t)(m0 + u) * 8192 + h * 4096 + lane * 8;
#pragma unroll
        for (int ks = 0; ks < 8; ++ks)
            a[u][ks] = *reinterpret_cast<const bf16x8*>(Ap + ks * 512);
    }
    {
        const char* Gsrc = (const char*)(Gfrag + (size_t)(bn * 4) * 8192);
#pragma unroll
        for (int i = 0; i < 8; ++i) {
            int f = (i * 512 + tid) * 16;
            gll16(Gsrc + f, (char*)sG + f);
        }
    }
    asm volatile("s_waitcnt vmcnt(0)" ::: "memory");
    __builtin_amdgcn_s_barrier();
    __builtin_amdgcn_sched_barrier(0);

    const f32x16 z16 = {0.f,0.f,0.f,0.f,0.f,0.f,0.f,0.f,0.f,0.f,0.f,0.f,0.f,0.f,0.f,0.f};
    f32x16 acc0, acc1;
    bf16x8 gf0[8], gf1[8];

    auto ldgf = [&](bf16x8 (&g)[8], const char* base) {
#pragma unroll
        for (int ks = 0; ks < 8; ++ks)
            g[ks] = *reinterpret_cast<const bf16x8*>(base + ks * 1024);
    };
    auto mmcl = [&](const bf16x8 (&gf)[8]) {
        acc0 = __builtin_amdgcn_mfma_f32_32x32x16_bf16(gf[0], a[0][0], z16, 0, 0, 0);
        acc1 = __builtin_amdgcn_mfma_f32_32x32x16_bf16(gf[0], a[1][0], z16, 0, 0, 0);
#pragma unroll
        for (int ks = 1; ks < 8; ++ks) {
            acc0 = __builtin_amdgcn_mfma_f32_32x32x16_bf16(gf[ks], a[0][ks], acc0, 0, 0, 0);
            acc1 = __builtin_amdgcn_mfma_f32_32x32x16_bf16(gf[ks], a[1][ks], acc1, 0, 0, 0);
        }
    };
    auto red16 = [&](const f32x16& v) -> float {
        float x0 = fmaxf(v[0], v[1]),  x1 = fmaxf(v[2], v[3]);
        float x2 = fmaxf(v[4], v[5]),  x3 = fmaxf(v[6], v[7]);
        float x4 = fmaxf(v[8], v[9]),  x5 = fmaxf(v[10], v[11]);
        float x6 = fmaxf(v[12], v[13]), x7 = fmaxf(v[14], v[15]);
        x0 = fmaxf(x0, x1); x2 = fmaxf(x2, x3);
        x4 = fmaxf(x4, x5); x6 = fmaxf(x6, x7);
        return fmaxf(fmaxf(x0, x2), fmaxf(x4, x6));
    };

#pragma unroll
    for (int s = 0; s < 4; ++s) {
        const char* gb = (const char*)sG + s * 16384 + lane * 16;
        ldgf(gf0, gb);            // qt0, compile-time LDS offsets
        ldgf(gf1, gb + 8192);     // qt1
        mmcl(gf0);
        float t0 = red16(acc0), t1 = red16(acc1);
        mmcl(gf1);
        t0 = fmaxf(t0, red16(acc0));
        t1 = fmaxf(t1, red16(acc1));
        t0 = fmaxf(t0, __shfl_xor(t0, 32));
        t1 = fmaxf(t1, __shfl_xor(t1, 32));
        const int n = bn * 4 + s;
        const float sv = hi ? t1 : t0;
        out[(size_t)(m0 + hi) * 4096 + n * 64 + h * 32 + l31] =
            fmaxf(sv, 0.f) + EPS_ADD;
    }
}

// ---------------------------------------------------------------------------
extern "C" void kernel_launch(void* const* d_in, const int* in_sizes, int n_in,
                              void* d_out, int out_size, void* d_ws, size_t ws_size,
                              hipStream_t stream) {
    const float* A  = (const float*)d_in[0];
    const float* B  = (const float*)d_in[1];
    const float* Wg = (const float*)d_in[2];
    float* out = (float*)d_out;

    bf16* Afrag = (bf16*)d_ws;                                      // 512 x 8192 bf16 = 8 MiB
    bf16* Gfrag = (bf16*)((char*)d_ws + (size_t)Mdim * Pdim * Cdim * sizeof(bf16)); // 64 x 8192 bf16

    prep_kernel<<<768, 256, 0, stream>>>(A, B, Wg, Afrag, Gfrag);
    gemm_max_kernel<<<1024, 512, 0, stream>>>(Afrag, Gfrag, out);   // 16 bn x 64 mg
}